// Round 5
// baseline (228.090 us; speedup 1.0000x reference)
//
#include <hip/hip_runtime.h>

typedef unsigned short u16;
typedef unsigned int u32;
typedef unsigned long long u64;
typedef __attribute__((ext_vector_type(8))) short s16x8;
typedef __attribute__((ext_vector_type(4))) float f32x4;

#if __has_builtin(__builtin_amdgcn_exp2f)
#define EXP2(x) __builtin_amdgcn_exp2f(x)
#else
#define EXP2(x) __expf((x) * 0.69314718f)
#endif

#if __has_builtin(__builtin_amdgcn_rcpf)
#define RCP(x) __builtin_amdgcn_rcpf(x)
#else
#define RCP(x) (1.0f / (x))
#endif

#define GLL(gp, lp) __builtin_amdgcn_global_load_lds(                         \
    (const __attribute__((address_space(1))) unsigned int*)(const void*)(gp), \
    (__attribute__((address_space(3))) unsigned int*)(void*)(lp), 16, 0, 0)

__device__ __forceinline__ u16 f2bf(float f) {
    union { float f; u32 u; } v; v.f = f;
    u32 r = v.u + 0x7FFF + ((v.u >> 16) & 1);
    return (u16)(r >> 16);
}

__device__ __forceinline__ u32 pack2_trunc(float a, float b) {
    union { float f; u32 u; } x, y; x.f = a; y.f = b;
    return (x.u >> 16) | (y.u & 0xFFFF0000u);
}

__device__ __forceinline__ float bf2f(u16 b) {
    union { u32 u; float f; } v; v.u = ((u32)b) << 16;
    return v.f;
}

__device__ __forceinline__ s16x8 scale_frag(s16x8 v, float s) {
    s16x8 o;
#pragma unroll
    for (int i = 0; i < 8; i++) o[i] = (short)f2bf(bf2f((u16)v[i]) * s);
    return o;
}

// ---------------- fused prep: x cast + both weight transposes in ONE launch ------
__global__ __launch_bounds__(256) void prep_fused(const float* __restrict__ x,
                                                  u16* __restrict__ x_bf,
                                                  const float* __restrict__ w_qkv,
                                                  u16* __restrict__ wqkvT,
                                                  const float* __restrict__ w_proj,
                                                  u16* __restrict__ wprojT) {
    __shared__ float tile[32][33];
    int bid = blockIdx.x, tid = threadIdx.x;
    if (bid < 8192) {
        size_t i = ((size_t)bid * 256 + tid) * 4;
        float4 f = *(const float4*)(x + i);
        u16 o[4] = { f2bf(f.x), f2bf(f.y), f2bf(f.z), f2bf(f.w) };
        *(u64*)(x_bf + i) =
            (u64)o[0] | ((u64)o[1] << 16) | ((u64)o[2] << 32) | ((u64)o[3] << 48);
        return;
    }
    const float* in;
    u16* out;
    int cols, bx, by;
    if (bid < 8192 + 3072) {
        int l = bid - 8192;
        in = w_qkv; out = wqkvT; cols = 3072; bx = l % 96; by = l / 96;
    } else {
        int l = bid - 11264;
        in = w_proj; out = wprojT; cols = 1024; bx = l & 31; by = l >> 5;
    }
    const int rows = 1024;
    int c0 = bx * 32, r0 = by * 32;
    int tx = tid & 31, ty = tid >> 5;   // 32 x 8
    for (int i = 0; i < 32; i += 8)
        tile[ty + i][tx] = in[(size_t)(r0 + ty + i) * cols + (c0 + tx)];
    __syncthreads();
    for (int i = 0; i < 32; i += 8)
        out[(size_t)(c0 + ty + i) * rows + (r0 + tx)] = f2bf(tile[tx][ty + i]);
}

// ============ QKV GEMM v2: 256x128 tile, 2-phase/K-step, counted vmcnt ===========
// C = A[8192][1024] * BT[3072][1024]^T + bias. 768 blocks = 3 EXACT rounds of 256
// (R2's 8-phase port was per-CU ~52% but its 384-block grid = 1.5 rounds ate it).
// 512 thr = 8 waves (4M x 2N), wave tile 64x64, BK=64, LDS 96KB (2-deep dbuf).
// Per K-step: P(kk) = {8 ds_read_b128; barrier; lgkmcnt(0); 16 MFMA; barrier} x2,
// then stage 6 GLLs for t+2 into the just-finished buffer (all reads provably
// drained: every wave's reads complete before its pre-MFMA lgkmcnt(0), and all
// waves passed the post-MFMA barrier) and vmcnt(6) = wait only t-1's stages
// (1 full tile in flight >> HBM latency). Never vmcnt(0) until the K-tail.
// BN=128 keeps the col-2048 Q|K / V boundary block-aligned for the MODE-1 split.
__global__ __launch_bounds__(512, 1) void gemm_qkv_p2(const u16* __restrict__ A,
                                                      const u16* __restrict__ BT,
                                                      const float* __restrict__ bias,
                                                      u16* __restrict__ qk,
                                                      u16* __restrict__ vT) {
    constexpr int K = 1024;
    __shared__ u16 SM[49152];            // 96 KB
    u16* As = SM;                        // 2 bufs x 16384 u16 (256 rows x 64)
    u16* Bs = SM + 32768;                // 2 bufs x 8192 u16  (128 rows x 64)

    int id = blockIdx.x;                 // 768 blocks, 96 per XCD
    int xcd = id & 7, j = id >> 3;
    int m0 = (xcd * 4 + j / 24) * 256;   // XCD m-stripe: 2MB A-panel per XCD L2
    int n0 = (j % 24) * 128;

    int tid = threadIdx.x, lane = tid & 63, w = tid >> 6;
    int row16 = lane & 15, quad = lane >> 4;
    int wm = w >> 1, wn = w & 1;         // 4M x 2N waves, wave tile 64x64
    int swz = row16 & 7;

    // staging: unit = 64 rows x 64 cols = 8KB = 512 thr x 16B. thread -> row tr,
    // source chunk tc XOR-swizzled so LDS[r][c] = global[r][c ^ (r&7)].
    int tr = tid >> 3, tc = (tid & 7) ^ (tr & 7);
    const u16* Ag = A + (size_t)(m0 + tr) * K + tc * 8;
    const u16* Bg = BT + (size_t)(n0 + tr) * K + tc * 8;

    int aBase = (wm * 64 + row16) * 64;
    int bBase = (wn * 64 + row16) * 64;

    f32x4 acc[4][4] = {};

#define STGALL(KO, BD) do {                                                    \
    _Pragma("unroll") for (int q = 0; q < 4; q++)                              \
        GLL(Ag + (size_t)(q * 64) * K + (KO), As + (BD) * 16384 + q * 4096 + tid * 8); \
    _Pragma("unroll") for (int u2 = 0; u2 < 2; u2++)                           \
        GLL(Bg + (size_t)(u2 * 64) * K + (KO), Bs + (BD) * 8192 + u2 * 4096 + tid * 8); \
} while (0)
#define BAR __builtin_amdgcn_s_barrier()
#define WAITL do {                                                             \
    asm volatile("s_waitcnt lgkmcnt(0)" ::: "memory");                         \
    __builtin_amdgcn_sched_barrier(0);                                         \
} while (0)
#define RD(KKv) do {                                                           \
    int cx = (((KKv) * 4 + quad) ^ swz) * 8;                                   \
    _Pragma("unroll") for (int m4 = 0; m4 < 4; m4++)                           \
        afr[m4] = *(const s16x8*)&As[bufo + aBase + m4 * 16 * 64 + cx];        \
    _Pragma("unroll") for (int nf = 0; nf < 4; nf++)                           \
        bfr[nf] = *(const s16x8*)&Bs[bufo2 + bBase + nf * 16 * 64 + cx];       \
} while (0)
#define MM do {                                                                \
    __builtin_amdgcn_s_setprio(1);                                             \
    _Pragma("unroll") for (int m4 = 0; m4 < 4; m4++)                           \
        _Pragma("unroll") for (int nf = 0; nf < 4; nf++)                       \
            acc[m4][nf] = __builtin_amdgcn_mfma_f32_16x16x32_bf16(             \
                afr[m4], bfr[nf], acc[m4][nf], 0, 0, 0);                       \
    __builtin_amdgcn_s_setprio(0);                                             \
} while (0)

    // prologue: tile0 -> buf0, tile1 -> buf1; wait tile0 (6 newest remain)
    STGALL(0, 0);
    STGALL(64, 1);
    asm volatile("s_waitcnt vmcnt(6)" ::: "memory");
    BAR;

    for (int t = 0; t < 16; ++t) {
        int buf = t & 1;
        int bufo = buf * 16384, bufo2 = buf * 8192;
        s16x8 afr[4], bfr[4];
        RD(0);
        BAR; WAITL; MM; BAR;
        RD(1);
        BAR; WAITL; MM; BAR;
        if (t < 14) {
            STGALL((size_t)(t + 2) * 64, buf);   // just-finished buffer: race-free
            asm volatile("s_waitcnt vmcnt(6)" ::: "memory");  // t-1's stages done
        } else if (t == 14) {
            asm volatile("s_waitcnt vmcnt(0)" ::: "memory");  // drain tail
        }
        BAR;
    }
#undef STGALL
#undef RD
#undef MM
#undef WAITL

    // ---------------- epilogue (MODE-1 split, block-uniform at BN=128) ----------
    if (n0 < 2048) {                     // Q|K region
#pragma unroll
        for (int nf = 0; nf < 4; nf++) {
            int col = n0 + wn * 64 + nf * 16 + row16;
            float bv = bias[col];
#pragma unroll
            for (int m4 = 0; m4 < 4; m4++)
#pragma unroll
                for (int r = 0; r < 4; r++)
                    qk[(size_t)(m0 + wm * 64 + m4 * 16 + quad * 4 + r) * 2048 + col] =
                        f2bf(acc[m4][nf][r] + bv);
        }
    } else {                             // V region: per-wave LDS transpose
        u16* scr = SM + w * 4608;        // 64 cols x 72-padded t
        __syncthreads();
#pragma unroll
        for (int nf = 0; nf < 4; nf++) {
            float bv = bias[n0 + wn * 64 + nf * 16 + row16];
#pragma unroll
            for (int m4 = 0; m4 < 4; m4++)
#pragma unroll
                for (int r = 0; r < 4; r++)
                    scr[(nf * 16 + row16) * 72 + (m4 * 16 + quad * 4 + r)] =
                        f2bf(acc[m4][nf][r] + bv);
        }
        __syncthreads();
        int r8 = lane >> 3, c8l = lane & 7;
        int vbase = (m0 >> 11) * 1024 + (n0 - 2048) + wn * 64;  // b*1024 + col0
        int tb = (m0 & 2047) + wm * 64;                         // t within batch
#pragma unroll
        for (int it = 0; it < 8; it++) {
            s16x8 vv = *(const s16x8*)&scr[(it * 8 + r8) * 72 + c8l * 8];
            *(s16x8*)&vT[(size_t)(vbase + it * 8 + r8) * 2048 + tb + c8l * 8] = vv;
        }
    }
}

// ---------------- GEMM: C = A[M][K] * BT[N][K]^T + bias, BK=64 (proj) ------------
template<int MODE, int NB>
__global__ __launch_bounds__(256, 4) void gemm_bt64(const u16* __restrict__ A,
                                                    const u16* __restrict__ BT,
                                                    const float* __restrict__ bias,
                                                    void* __restrict__ O1,
                                                    u16* __restrict__ vT,
                                                    int M, int N, int K) {
    __shared__ u16 SMEM[18432];
    u16* As = SMEM;
    u16* Bs = SMEM + 8192;
    int id = blockIdx.x;
    int xcd = id & 7, s = id >> 3;
    int ni = s % NB, mi8 = s / NB;
    int n0 = ni * 128, m0 = (xcd * 8 + mi8) * 128;
    int tid = threadIdx.x, lane = tid & 63, w = tid >> 6;
    int row16 = lane & 15, quad = lane >> 4;
    int wm = (w >> 1) * 64, wn = (w & 1) * 64;
    f32x4 acc[4][4] = {};

    int lr = lane >> 3;
    int cswz = (lane & 7) ^ lr;
    const u16* Ag = A + (size_t)(m0 + w * 32 + lr) * K + cswz * 8;
    const u16* Bg = BT + (size_t)(n0 + w * 32 + lr) * K + cswz * 8;
    u16* Asl = As + (w * 32) * 64;
    u16* Bsl = Bs + (w * 32) * 64;

    for (int k0 = 0; k0 < K; k0 += 64) {
        __syncthreads();
#pragma unroll
        for (int j = 0; j < 4; j++) {
            GLL(Ag + k0 + (size_t)j * 8 * K, Asl + j * 8 * 64);
            GLL(Bg + k0 + (size_t)j * 8 * K, Bsl + j * 8 * 64);
        }
        __syncthreads();
#pragma unroll
        for (int kk = 0; kk < 2; kk++) {
            s16x8 af[4], bf[4];
#pragma unroll
            for (int mi = 0; mi < 4; mi++)
                af[mi] = *(const s16x8*)&As[(wm + mi * 16 + row16) * 64 +
                                            (((kk * 4 + quad) ^ (row16 & 7)) * 8)];
#pragma unroll
            for (int ni2 = 0; ni2 < 4; ni2++)
                bf[ni2] = *(const s16x8*)&Bs[(wn + ni2 * 16 + row16) * 64 +
                                             (((kk * 4 + quad) ^ (row16 & 7)) * 8)];
#pragma unroll
            for (int mi = 0; mi < 4; mi++)
#pragma unroll
                for (int ni2 = 0; ni2 < 4; ni2++)
                    acc[mi][ni2] = __builtin_amdgcn_mfma_f32_16x16x32_bf16(
                        af[mi], bf[ni2], acc[mi][ni2], 0, 0, 0);
        }
    }

    if (MODE == 0) {
        float* O = (float*)O1;
#pragma unroll
        for (int ni2 = 0; ni2 < 4; ni2++) {
            int col = n0 + wn + ni2 * 16 + row16;
            float bv = bias[col];
#pragma unroll
            for (int mi = 0; mi < 4; mi++)
#pragma unroll
                for (int r = 0; r < 4; r++)
                    O[(size_t)(m0 + wm + mi * 16 + quad * 4 + r) * N + col] =
                        acc[mi][ni2][r] + bv;
        }
    } else if (n0 < 2048) {
        u16* qk = (u16*)O1;
#pragma unroll
        for (int ni2 = 0; ni2 < 4; ni2++) {
            int col = n0 + wn + ni2 * 16 + row16;
            float bv = bias[col];
#pragma unroll
            for (int mi = 0; mi < 4; mi++)
#pragma unroll
                for (int r = 0; r < 4; r++)
                    qk[(size_t)(m0 + wm + mi * 16 + quad * 4 + r) * 2048 + col] =
                        f2bf(acc[mi][ni2][r] + bv);
        }
    } else {
        __syncthreads();
        u16* scr = SMEM + w * 64 * 72;
#pragma unroll
        for (int ni2 = 0; ni2 < 4; ni2++) {
            float bv = bias[n0 + wn + ni2 * 16 + row16];
#pragma unroll
            for (int mi = 0; mi < 4; mi++)
#pragma unroll
                for (int r = 0; r < 4; r++)
                    scr[(ni2 * 16 + row16) * 72 + (mi * 16 + quad * 4 + r)] =
                        f2bf(acc[mi][ni2][r] + bv);
        }
        __syncthreads();
        int r8 = lane >> 3, c8 = lane & 7;
        int vbase = (m0 >> 11) * 1024 + (n0 - 2048) + wn;
        int tb = (m0 & 2047) + wm;
#pragma unroll
        for (int it = 0; it < 8; it++) {
            s16x8 vv = *(const s16x8*)&scr[(it * 8 + r8) * 72 + c8 * 8];
            *(s16x8*)&vT[(size_t)(vbase + it * 8 + r8) * 2048 + tb + c8 * 8] = vv;
        }
    }
}

// ---------------- flash attention (causal, no-max softmax, S^T form) -------------
__global__ __launch_bounds__(256, 2) void attn_kernel(const u16* __restrict__ qk,
                                                      const u16* __restrict__ vT,
                                                      u16* __restrict__ y) {
    __shared__ u16 Kb[2][4096];
    __shared__ u16 Vb[2][4096];
    __shared__ u16 Ps[4][2048];

    int tid = threadIdx.x, lane = tid & 63, w = tid >> 6;
    int row16 = lane & 15, quad = lane >> 4;
    int id = blockIdx.x;                 // 0..1023
    int xcd = id & 7, slot = id >> 3;
    int qt = 15 - (slot >> 3);           // heavy tiles first
    int bh = ((slot & 7) << 3) | xcd;
    int b = bh >> 4, h = bh & 15;
    const u16* qkb = qk + (size_t)b * 2048 * 2048;
    const u16* vtb = vT + ((size_t)(b * 1024) + h * 64) * 2048;

    int lr = lane >> 3, cswz = (lane & 7) ^ lr;
    const u16* Kg = qkb + (size_t)(w * 16 + lr) * 2048 + 1024 + h * 64 + cswz * 8;
    const u16* Vg = vtb + (size_t)(w * 16 + lr) * 2048 + cswz * 8;
    u16* Psw = Ps[w];
    int sw = row16 & 7;

    s16x8 ones;
#pragma unroll
    for (int i = 0; i < 8; i++) ones[i] = (short)0x3F80;
    const float qs = 0.125f * 1.44269504f;

    int q0 = qt * 128;
    int niter = 2 * qt + 2;
    int qw = q0 + w * 32;

    s16x8 qf[2][2];
#pragma unroll
    for (int mi = 0; mi < 2; mi++) {
        const u16* qp = qkb + (size_t)(qw + mi * 16 + row16) * 2048 + h * 64 + quad * 8;
        qf[mi][0] = scale_frag(*(const s16x8*)qp, qs);
        qf[mi][1] = scale_frag(*(const s16x8*)(qp + 32), qs);
    }

    f32x4 acc_o[2][4] = {};
    f32x4 acc_l[2] = {};

#pragma unroll
    for (int j = 0; j < 2; j++) {
        GLL(Kg + (size_t)j * 8 * 2048, Kb[0] + w * 16 * 64 + j * 8 * 64);
        GLL(Vg + (size_t)j * 8 * 2048, Vb[0] + w * 16 * 64 + j * 8 * 64);
    }

    for (int kb = 0; kb < niter; kb++) {
        int cur = kb & 1;
        __syncthreads();
        if (kb + 1 < niter) {
            int k1 = (kb + 1) * 64;
#pragma unroll
            for (int j = 0; j < 2; j++) {
                GLL(Kg + (size_t)(k1 + j * 8) * 2048, Kb[cur ^ 1] + w * 16 * 64 + j * 8 * 64);
                GLL(Vg + k1 + (size_t)j * 8 * 2048, Vb[cur ^ 1] + w * 16 * 64 + j * 8 * 64);
            }
        }
        int k0 = kb * 64;
        if (k0 > qw + 31) continue;
        const u16* Kc = Kb[cur];
        const u16* Vc = Vb[cur];

        f32x4 sc[2][4];
#pragma unroll
        for (int nk = 0; nk < 4; nk++) {
            s16x8 kf0 = *(const s16x8*)&Kc[(nk * 16 + row16) * 64 + ((quad ^ sw) * 8)];
            s16x8 kf1 = *(const s16x8*)&Kc[(nk * 16 + row16) * 64 + (((4 + quad) ^ sw) * 8)];
#pragma unroll
            for (int mi = 0; mi < 2; mi++) {
                f32x4 z = {};
                z = __builtin_amdgcn_mfma_f32_16x16x32_bf16(kf0, qf[mi][0], z, 0, 0, 0);
                z = __builtin_amdgcn_mfma_f32_16x16x32_bf16(kf1, qf[mi][1], z, 0, 0, 0);
                sc[mi][nk] = z;
            }
        }
        if (k0 + 63 > qw) {
#pragma unroll
            for (int mi = 0; mi < 2; mi++) {
                int qg = qw + mi * 16 + row16;
#pragma unroll
                for (int nk = 0; nk < 4; nk++) {
                    int kbase = k0 + nk * 16 + quad * 4;
#pragma unroll
                    for (int r = 0; r < 4; r++)
                        if (kbase + r > qg) sc[mi][nk][r] = -__builtin_inff();
                }
            }
        }
#pragma unroll
        for (int mi = 0; mi < 2; mi++)
#pragma unroll
            for (int nk = 0; nk < 4; nk++) {
                float p0 = EXP2(sc[mi][nk][0]);
                float p1 = EXP2(sc[mi][nk][1]);
                float p2 = EXP2(sc[mi][nk][2]);
                float p3 = EXP2(sc[mi][nk][3]);
                u32 w0 = pack2_trunc(p0, p1);
                u32 w1 = pack2_trunc(p2, p3);
                int u = nk * 2 + (quad >> 1);
                int eo = ((u ^ sw) * 8) + (quad & 1) * 4;
                *(u64*)&Psw[mi * 1024 + row16 * 64 + eo] = (u64)w0 | ((u64)w1 << 32);
            }
#pragma unroll
        for (int kk = 0; kk < 2; kk++) {
            int co = ((kk * 4 + quad) ^ sw) * 8;
            s16x8 pf0 = *(const s16x8*)&Psw[row16 * 64 + co];
            s16x8 pf1 = *(const s16x8*)&Psw[1024 + row16 * 64 + co];
#pragma unroll
            for (int nd = 0; nd < 4; nd++) {
                s16x8 vf = *(const s16x8*)&Vc[(nd * 16 + row16) * 64 + co];
                acc_o[0][nd] = __builtin_amdgcn_mfma_f32_16x16x32_bf16(pf0, vf, acc_o[0][nd], 0, 0, 0);
                acc_o[1][nd] = __builtin_amdgcn_mfma_f32_16x16x32_bf16(pf1, vf, acc_o[1][nd], 0, 0, 0);
            }
            acc_l[0] = __builtin_amdgcn_mfma_f32_16x16x32_bf16(pf0, ones, acc_l[0], 0, 0, 0);
            acc_l[1] = __builtin_amdgcn_mfma_f32_16x16x32_bf16(pf1, ones, acc_l[1], 0, 0, 0);
        }
    }

#pragma unroll
    for (int mi = 0; mi < 2; mi++) {
        int t0 = qw + mi * 16 + quad * 4;
#pragma unroll
        for (int r = 0; r < 4; r++) {
            float inv = RCP(acc_l[mi][r]);
#pragma unroll
            for (int nd = 0; nd < 4; nd++)
                y[((size_t)b * 2048 + t0 + r) * 1024 + h * 64 + nd * 16 + row16] =
                    f2bf(acc_o[mi][nd][r] * inv);
        }
    }
}

extern "C" void kernel_launch(void* const* d_in, const int* in_sizes, int n_in,
                              void* d_out, int out_size, void* d_ws, size_t ws_size,
                              hipStream_t stream) {
    const float* x      = (const float*)d_in[0];
    const float* w_qkv  = (const float*)d_in[1];
    const float* b_qkv  = (const float*)d_in[2];
    const float* w_proj = (const float*)d_in[3];
    const float* b_proj = (const float*)d_in[4];
    float* out = (float*)d_out;

    u16* ws     = (u16*)d_ws;
    u16* x_bf   = ws;                               // 8192*1024
    u16* wqkvT  = x_bf  + (size_t)8192 * 1024;      // 3072*1024
    u16* wprojT = wqkvT + (size_t)3072 * 1024;      // 1024*1024
    u16* qkbuf  = wprojT + (size_t)1024 * 1024;     // 8192*2048 (Q|K)
    u16* vT     = qkbuf + (size_t)8192 * 2048;      // 4096*2048 (V transposed)
    u16* ybf    = vT    + (size_t)4096 * 2048;      // 8192*1024

    prep_fused<<<dim3(12288), dim3(256), 0, stream>>>(x, x_bf, w_qkv, wqkvT, w_proj, wprojT);
    gemm_qkv_p2<<<dim3(768), dim3(512), 0, stream>>>(x_bf, wqkvT, b_qkv, qkbuf, vT);
    attn_kernel<<<dim3(1024), 256, 0, stream>>>(qkbuf, vT, ybf);
    gemm_bt64<0, 8><<<dim3(512), 256, 0, stream>>>(ybf, wprojT, b_proj, (void*)out, nullptr, 8192, 1024, 1024);
}

// Round 6
// 224.956 us; speedup vs baseline: 1.0139x; 1.0139x over previous
//
#include <hip/hip_runtime.h>

typedef unsigned short u16;
typedef unsigned int u32;
typedef unsigned long long u64;
typedef __attribute__((ext_vector_type(8))) short s16x8;
typedef __attribute__((ext_vector_type(4))) float f32x4;

#if __has_builtin(__builtin_amdgcn_exp2f)
#define EXP2(x) __builtin_amdgcn_exp2f(x)
#else
#define EXP2(x) __expf((x) * 0.69314718f)
#endif

#if __has_builtin(__builtin_amdgcn_rcpf)
#define RCP(x) __builtin_amdgcn_rcpf(x)
#else
#define RCP(x) (1.0f / (x))
#endif

#define GLL(gp, lp) __builtin_amdgcn_global_load_lds(                         \
    (const __attribute__((address_space(1))) unsigned int*)(const void*)(gp), \
    (__attribute__((address_space(3))) unsigned int*)(void*)(lp), 16, 0, 0)

__device__ __forceinline__ u16 f2bf(float f) {
    union { float f; u32 u; } v; v.f = f;
    u32 r = v.u + 0x7FFF + ((v.u >> 16) & 1);
    return (u16)(r >> 16);
}

__device__ __forceinline__ u32 pack2_trunc(float a, float b) {
    union { float f; u32 u; } x, y; x.f = a; y.f = b;
    return (x.u >> 16) | (y.u & 0xFFFF0000u);
}

__device__ __forceinline__ float bf2f(u16 b) {
    union { u32 u; float f; } v; v.u = ((u32)b) << 16;
    return v.f;
}

__device__ __forceinline__ s16x8 scale_frag(s16x8 v, float s) {
    s16x8 o;
#pragma unroll
    for (int i = 0; i < 8; i++) o[i] = (short)f2bf(bf2f((u16)v[i]) * s);
    return o;
}

// ---------------- fused prep: x cast + both weight transposes in ONE launch ------
__global__ __launch_bounds__(256) void prep_fused(const float* __restrict__ x,
                                                  u16* __restrict__ x_bf,
                                                  const float* __restrict__ w_qkv,
                                                  u16* __restrict__ wqkvT,
                                                  const float* __restrict__ w_proj,
                                                  u16* __restrict__ wprojT) {
    __shared__ float tile[32][33];
    int bid = blockIdx.x, tid = threadIdx.x;
    if (bid < 8192) {
        size_t i = ((size_t)bid * 256 + tid) * 4;
        float4 f = *(const float4*)(x + i);
        u16 o[4] = { f2bf(f.x), f2bf(f.y), f2bf(f.z), f2bf(f.w) };
        *(u64*)(x_bf + i) =
            (u64)o[0] | ((u64)o[1] << 16) | ((u64)o[2] << 32) | ((u64)o[3] << 48);
        return;
    }
    const float* in;
    u16* out;
    int cols, bx, by;
    if (bid < 8192 + 3072) {
        int l = bid - 8192;
        in = w_qkv; out = wqkvT; cols = 3072; bx = l % 96; by = l / 96;
    } else {
        int l = bid - 11264;
        in = w_proj; out = wprojT; cols = 1024; bx = l & 31; by = l >> 5;
    }
    const int rows = 1024;
    int c0 = bx * 32, r0 = by * 32;
    int tx = tid & 31, ty = tid >> 5;   // 32 x 8
    for (int i = 0; i < 32; i += 8)
        tile[ty + i][tx] = in[(size_t)(r0 + ty + i) * cols + (c0 + tx)];
    __syncthreads();
    for (int i = 0; i < 32; i += 8)
        out[(size_t)(c0 + ty + i) * rows + (r0 + tx)] = f2bf(tile[tx][ty + i]);
}

// ---------------- GEMM: C = A[M][K] * BT[N][K]^T + bias, BK=64, XOR-swizzled LDS ---
// Flat grid with XCD m-stripe swizzle: m0 = (xcd*8 + mi8)*128 keeps each XCD's
// A-stripe (2 MB) resident in its private L2. Requires M = 8192 (64 m-blocks).
// MODE 0: fp32 out to O1[M][N].
// MODE 1: QKV split -- col<2048 -> bf16 qk[M][2048]; col>=2048 -> vT via LDS transpose
// STRUCTURE NOTE (R2/R5 post-mortems): two pipelined restructures both lost to
// this 2-barrier 128^2 structure at K=1024:
//   R2 8-phase 256^2 (384 blk = 1.5 rounds): 70.8 us; R5 2-phase 256x128 (4Mx2N
//   waves -> 128KB LDS read/K-tile vs 1032cyc MFMA, LDS-pipe-bound ceiling 67%,
//   serialized by lgkmcnt(0)): 74.4 us. This kernel: 58.1 us (858 TF), 4 blk/CU
//   wave-overlap. Keeper.
template<int MODE, int NB>
__global__ __launch_bounds__(256, 4) void gemm_bt64(const u16* __restrict__ A,
                                                    const u16* __restrict__ BT,
                                                    const float* __restrict__ bias,
                                                    void* __restrict__ O1,
                                                    u16* __restrict__ vT,
                                                    int M, int N, int K) {
    __shared__ u16 SMEM[18432];  // 36864 B: K-loop uses 32 KB; epilogue scratch 36 KB
    u16* As = SMEM;
    u16* Bs = SMEM + 8192;
    int id = blockIdx.x;
    int xcd = id & 7, s = id >> 3;
    int ni = s % NB, mi8 = s / NB;
    int n0 = ni * 128, m0 = (xcd * 8 + mi8) * 128;
    int tid = threadIdx.x, lane = tid & 63, w = tid >> 6;
    int row16 = lane & 15, quad = lane >> 4;
    int wm = (w >> 1) * 64, wn = (w & 1) * 64;
    f32x4 acc[4][4] = {};

    int lr = lane >> 3;            // row-in-8 of staged row
    int cswz = (lane & 7) ^ lr;    // swizzled source column chunk
    const u16* Ag = A + (size_t)(m0 + w * 32 + lr) * K + cswz * 8;
    const u16* Bg = BT + (size_t)(n0 + w * 32 + lr) * K + cswz * 8;
    u16* Asl = As + (w * 32) * 64;
    u16* Bsl = Bs + (w * 32) * 64;

    for (int k0 = 0; k0 < K; k0 += 64) {
        __syncthreads();
#pragma unroll
        for (int j = 0; j < 4; j++) {
            GLL(Ag + k0 + (size_t)j * 8 * K, Asl + j * 8 * 64);
            GLL(Bg + k0 + (size_t)j * 8 * K, Bsl + j * 8 * 64);
        }
        __syncthreads();
#pragma unroll
        for (int kk = 0; kk < 2; kk++) {
            s16x8 af[4], bf[4];
#pragma unroll
            for (int mi = 0; mi < 4; mi++)
                af[mi] = *(const s16x8*)&As[(wm + mi * 16 + row16) * 64 +
                                            (((kk * 4 + quad) ^ (row16 & 7)) * 8)];
#pragma unroll
            for (int ni2 = 0; ni2 < 4; ni2++)
                bf[ni2] = *(const s16x8*)&Bs[(wn + ni2 * 16 + row16) * 64 +
                                             (((kk * 4 + quad) ^ (row16 & 7)) * 8)];
#pragma unroll
            for (int mi = 0; mi < 4; mi++)
#pragma unroll
                for (int ni2 = 0; ni2 < 4; ni2++)
                    acc[mi][ni2] = __builtin_amdgcn_mfma_f32_16x16x32_bf16(
                        af[mi], bf[ni2], acc[mi][ni2], 0, 0, 0);
        }
    }

    if (MODE == 0) {
        float* O = (float*)O1;
#pragma unroll
        for (int ni2 = 0; ni2 < 4; ni2++) {
            int col = n0 + wn + ni2 * 16 + row16;
            float bv = bias[col];
#pragma unroll
            for (int mi = 0; mi < 4; mi++)
#pragma unroll
                for (int r = 0; r < 4; r++)
                    O[(size_t)(m0 + wm + mi * 16 + quad * 4 + r) * N + col] =
                        acc[mi][ni2][r] + bv;
        }
    } else if (n0 < 2048) {  // Q|K region (block-uniform)
        u16* qk = (u16*)O1;
#pragma unroll
        for (int ni2 = 0; ni2 < 4; ni2++) {
            int col = n0 + wn + ni2 * 16 + row16;
            float bv = bias[col];
#pragma unroll
            for (int mi = 0; mi < 4; mi++)
#pragma unroll
                for (int r = 0; r < 4; r++)
                    qk[(size_t)(m0 + wm + mi * 16 + quad * 4 + r) * 2048 + col] =
                        f2bf(acc[mi][ni2][r] + bv);
        }
    } else {  // V region: transpose via per-wave LDS scratch, coalesced 16B stores
        __syncthreads();                      // K-loop LDS reads done
        u16* scr = SMEM + w * 64 * 72;        // 64 rows (c) x 72-padded (t)
#pragma unroll
        for (int ni2 = 0; ni2 < 4; ni2++) {
            float bv = bias[n0 + wn + ni2 * 16 + row16];
#pragma unroll
            for (int mi = 0; mi < 4; mi++)
#pragma unroll
                for (int r = 0; r < 4; r++)
                    scr[(ni2 * 16 + row16) * 72 + (mi * 16 + quad * 4 + r)] =
                        f2bf(acc[mi][ni2][r] + bv);
        }
        __syncthreads();                      // drain LDS writes (lgkm)
        int r8 = lane >> 3, c8 = lane & 7;
        int vbase = (m0 >> 11) * 1024 + (n0 - 2048) + wn;  // b*1024 + c0
        int tb = (m0 & 2047) + wm;                         // t within batch
#pragma unroll
        for (int it = 0; it < 8; it++) {
            s16x8 vv = *(const s16x8*)&scr[(it * 8 + r8) * 72 + c8 * 8];
            *(s16x8*)&vT[(size_t)(vbase + it * 8 + r8) * 2048 + tb + c8 * 8] = vv;
        }
    }
}

// ---------------- flash attention (causal, no-max softmax, S^T form) -------------
// qk: [B*T][2048] bf16 (Q cols 0..1023, K cols 1024..2047)
// vT: [(b*1024 + h*64 + d)][2048] bf16 ; y: [B*T][1024] bf16
// ONE 128-row q-tile per block, 32 rows/wave; 1024 blocks.
// qt mapping is a BALANCED bijection (pairi -> 15,0,14,1,13,2,...): every
// dispatch round of 256 blocks sums to exactly 68 kv-iters per CU (the old
// heavy-first order gave round sums 32+24+16+8 = 80-iter critical path).
// XCD decode keeps all blocks of one bh on XCD bh%8.
__global__ __launch_bounds__(256, 2) void attn_kernel(const u16* __restrict__ qk,
                                                      const u16* __restrict__ vT,
                                                      u16* __restrict__ y) {
    __shared__ u16 Kb[2][4096];
    __shared__ u16 Vb[2][4096];
    __shared__ u16 Ps[4][2048];   // per wave: 2 mi x 16 rows x 64 keys

    int tid = threadIdx.x, lane = tid & 63, w = tid >> 6;
    int row16 = lane & 15, quad = lane >> 4;
    int id = blockIdx.x;                 // 0..1023
    int xcd = id & 7, slot = id >> 3;    // slot 0..127
    int pairi = slot >> 3;               // 0..15
    int qt = (pairi & 1) ? (pairi >> 1) : (15 - (pairi >> 1));  // balanced rounds
    int bh = ((slot & 7) << 3) | xcd;    // all blocks of bh on XCD bh%8
    int b = bh >> 4, h = bh & 15;
    const u16* qkb = qk + (size_t)b * 2048 * 2048;
    const u16* vtb = vT + ((size_t)(b * 1024) + h * 64) * 2048;

    int lr = lane >> 3, cswz = (lane & 7) ^ lr;
    const u16* Kg = qkb + (size_t)(w * 16 + lr) * 2048 + 1024 + h * 64 + cswz * 8;
    const u16* Vg = vtb + (size_t)(w * 16 + lr) * 2048 + cswz * 8;
    u16* Psw = Ps[w];
    int sw = row16 & 7;

    s16x8 ones;
#pragma unroll
    for (int i = 0; i < 8; i++) ones[i] = (short)0x3F80;  // bf16 1.0
    const float qs = 0.125f * 1.44269504f;                // 1/sqrt(64) * log2(e)

    int q0 = qt * 128;
    int niter = 2 * qt + 2;
    int qw = q0 + w * 32;                  // this wave's first q-row

    s16x8 qf[2][2];
#pragma unroll
    for (int mi = 0; mi < 2; mi++) {
        const u16* qp = qkb + (size_t)(qw + mi * 16 + row16) * 2048 + h * 64 + quad * 8;
        qf[mi][0] = scale_frag(*(const s16x8*)qp, qs);
        qf[mi][1] = scale_frag(*(const s16x8*)(qp + 32), qs);
    }

    f32x4 acc_o[2][4] = {};
    f32x4 acc_l[2] = {};

#pragma unroll
    for (int j = 0; j < 2; j++) {  // prologue prefetch k-block 0 -> buf 0
        GLL(Kg + (size_t)j * 8 * 2048, Kb[0] + w * 16 * 64 + j * 8 * 64);
        GLL(Vg + (size_t)j * 8 * 2048, Vb[0] + w * 16 * 64 + j * 8 * 64);
    }

    for (int kb = 0; kb < niter; kb++) {
        int cur = kb & 1;
        __syncthreads();  // drains GLLs for cur + joins waves
        if (kb + 1 < niter) {
            int k1 = (kb + 1) * 64;
#pragma unroll
            for (int j = 0; j < 2; j++) {
                GLL(Kg + (size_t)(k1 + j * 8) * 2048, Kb[cur ^ 1] + w * 16 * 64 + j * 8 * 64);
                GLL(Vg + k1 + (size_t)j * 8 * 2048, Vb[cur ^ 1] + w * 16 * 64 + j * 8 * 64);
            }
        }
        int k0 = kb * 64;
        if (k0 > qw + 31) continue;  // wave-uniform: fully-masked for this wave
        const u16* Kc = Kb[cur];
        const u16* Vc = Vb[cur];

        // S^T = K Q^T : lane holds (q=row16 fixed, keys quad*4+r of tile nk)
        f32x4 sc[2][4];
#pragma unroll
        for (int nk = 0; nk < 4; nk++) {
            s16x8 kf0 = *(const s16x8*)&Kc[(nk * 16 + row16) * 64 + ((quad ^ sw) * 8)];
            s16x8 kf1 = *(const s16x8*)&Kc[(nk * 16 + row16) * 64 + (((4 + quad) ^ sw) * 8)];
#pragma unroll
            for (int mi = 0; mi < 2; mi++) {
                f32x4 z = {};
                z = __builtin_amdgcn_mfma_f32_16x16x32_bf16(kf0, qf[mi][0], z, 0, 0, 0);
                z = __builtin_amdgcn_mfma_f32_16x16x32_bf16(kf1, qf[mi][1], z, 0, 0, 0);
                sc[mi][nk] = z;
            }
        }
        if (k0 + 63 > qw) {  // diagonal region: causal mask (key > q -> -inf)
#pragma unroll
            for (int mi = 0; mi < 2; mi++) {
                int qg = qw + mi * 16 + row16;
#pragma unroll
                for (int nk = 0; nk < 4; nk++) {
                    int kbase = k0 + nk * 16 + quad * 4;
#pragma unroll
                    for (int r = 0; r < 4; r++)
                        if (kbase + r > qg) sc[mi][nk][r] = -__builtin_inff();
                }
            }
        }
        // exp2 -> P[q][key] rows in LDS via packed b64 (XOR-swizzled 16B units)
#pragma unroll
        for (int mi = 0; mi < 2; mi++)
#pragma unroll
            for (int nk = 0; nk < 4; nk++) {
                float p0 = EXP2(sc[mi][nk][0]);
                float p1 = EXP2(sc[mi][nk][1]);
                float p2 = EXP2(sc[mi][nk][2]);
                float p3 = EXP2(sc[mi][nk][3]);
                u32 w0 = pack2_trunc(p0, p1);
                u32 w1 = pack2_trunc(p2, p3);
                int u = nk * 2 + (quad >> 1);
                int eo = ((u ^ sw) * 8) + (quad & 1) * 4;
                *(u64*)&Psw[mi * 1024 + row16 * 64 + eo] = (u64)w0 | ((u64)w1 << 32);
            }
        // P (A-layout) x V^T (B-layout); row-sums via ones-MFMA
#pragma unroll
        for (int kk = 0; kk < 2; kk++) {
            int co = ((kk * 4 + quad) ^ sw) * 8;
            s16x8 pf0 = *(const s16x8*)&Psw[row16 * 64 + co];
            s16x8 pf1 = *(const s16x8*)&Psw[1024 + row16 * 64 + co];
#pragma unroll
            for (int nd = 0; nd < 4; nd++) {
                s16x8 vf = *(const s16x8*)&Vc[(nd * 16 + row16) * 64 + co];
                acc_o[0][nd] = __builtin_amdgcn_mfma_f32_16x16x32_bf16(pf0, vf, acc_o[0][nd], 0, 0, 0);
                acc_o[1][nd] = __builtin_amdgcn_mfma_f32_16x16x32_bf16(pf1, vf, acc_o[1][nd], 0, 0, 0);
            }
            acc_l[0] = __builtin_amdgcn_mfma_f32_16x16x32_bf16(pf0, ones, acc_l[0], 0, 0, 0);
            acc_l[1] = __builtin_amdgcn_mfma_f32_16x16x32_bf16(pf1, ones, acc_l[1], 0, 0, 0);
        }
    }

    // epilogue: O / l -> y bf16
#pragma unroll
    for (int mi = 0; mi < 2; mi++) {
        int t0 = qw + mi * 16 + quad * 4;
#pragma unroll
        for (int r = 0; r < 4; r++) {
            float inv = RCP(acc_l[mi][r]);
#pragma unroll
            for (int nd = 0; nd < 4; nd++)
                y[((size_t)b * 2048 + t0 + r) * 1024 + h * 64 + nd * 16 + row16] =
                    f2bf(acc_o[mi][nd][r] * inv);
        }
    }
}

extern "C" void kernel_launch(void* const* d_in, const int* in_sizes, int n_in,
                              void* d_out, int out_size, void* d_ws, size_t ws_size,
                              hipStream_t stream) {
    const float* x      = (const float*)d_in[0];
    const float* w_qkv  = (const float*)d_in[1];
    const float* b_qkv  = (const float*)d_in[2];
    const float* w_proj = (const float*)d_in[3];
    const float* b_proj = (const float*)d_in[4];
    float* out = (float*)d_out;

    u16* ws     = (u16*)d_ws;
    u16* x_bf   = ws;                               // 8192*1024
    u16* wqkvT  = x_bf  + (size_t)8192 * 1024;      // 3072*1024
    u16* wprojT = wqkvT + (size_t)3072 * 1024;      // 1024*1024
    u16* qkbuf  = wprojT + (size_t)1024 * 1024;     // 8192*2048 (Q|K)
    u16* vT     = qkbuf + (size_t)8192 * 2048;      // 4096*2048 (V transposed)
    u16* ybf    = vT    + (size_t)4096 * 2048;      // 8192*1024

    prep_fused<<<dim3(12288), dim3(256), 0, stream>>>(x, x_bf, w_qkv, wqkvT, w_proj, wprojT);
    gemm_bt64<1, 24><<<dim3(1536), 256, 0, stream>>>(x_bf, wqkvT, b_qkv, (void*)qkbuf, vT, 8192, 3072, 1024);
    attn_kernel<<<dim3(1024), 256, 0, stream>>>(qkbuf, vT, ybf);
    gemm_bt64<0, 8><<<dim3(512), 256, 0, stream>>>(ybf, wprojT, b_proj, (void*)out, nullptr, 8192, 1024, 1024);
}